// Round 1
// baseline (49.741 us; speedup 1.0000x reference)
//
#include <hip/hip_runtime.h>
#include <stdint.h>

#define B_ 4
#define C_ 1
#define D_ 128
#define HW_ 65536          // 256*256
#define K_ 4
#define NBC (B_*C_)
#define GPB (HW_/4)        // float4 groups per (b,c) per depth-slice = 16384
#define SCALE_ 100000.0f
#define EPS_ 1e-15f

__global__ __launch_bounds__(64) void init_mm_kernel(unsigned int* mm) {
    int t = threadIdx.x;
    if (t < NBC) {
        mm[2*t]   = 0x7F800000u;  // +inf  (min slot)
        mm[2*t+1] = 0u;           // 0.0f  (max slot; all values >= 0)
    }
}

__device__ __forceinline__ void cswap_u64(unsigned long long& hi, unsigned long long& lo) {
    unsigned long long a = hi, b = lo;
    bool sw = b > a;
    hi = sw ? b : a;
    lo = sw ? a : b;
}

// Each thread: 4 consecutive (h,w) columns (one float4 group), half of the depth range.
// Partner lane (lane^1) handles the other depth half; merge via shuffles.
__global__ __launch_bounds__(256) void topk_kernel(const float* __restrict__ x,
                                                   float* __restrict__ out,
                                                   unsigned int* __restrict__ mm) {
    const int gt   = blockIdx.x * 256 + threadIdx.x;
    const int half = gt & 1;
    const int gidx = gt >> 1;               // column-group id over all (b,c)
    const int bc   = gidx / GPB;
    const int grp  = gidx - bc * GPB;

    const float4* __restrict__ src = (const float4*)x
        + (size_t)bc * D_ * GPB + (size_t)half * (D_/2) * GPB + grp;

    // top-4 lists per column j: sorted desc by value; ties keep earlier index on top
    float lv[4][K_];
    int   li[4][K_];
    #pragma unroll
    for (int j = 0; j < 4; ++j)
        #pragma unroll
        for (int k = 0; k < K_; ++k) { lv[j][k] = -1.0f; li[j][k] = 0; }

    float mn = __int_as_float(0x7F800000);  // +inf

    const int dbase = half * (D_/2);
    #pragma unroll 4
    for (int dd = 0; dd < D_/2; ++dd) {
        const float4 q = src[(size_t)dd * GPB];
        const int d = dbase + dd;
        float vx[4] = { fmaxf(q.x, 0.0f), fmaxf(q.y, 0.0f),
                        fmaxf(q.z, 0.0f), fmaxf(q.w, 0.0f) };
        #pragma unroll
        for (int j = 0; j < 4; ++j) {
            const float v = vx[j];
            mn = fminf(mn, v);
            // insert at bottom (strict >: equal value keeps earlier index)
            const bool ins = v > lv[j][3];
            lv[j][3] = ins ? v : lv[j][3];
            li[j][3] = ins ? d : li[j][3];
            // bubble up (strict >: stable for ties)
            #pragma unroll
            for (int k = 3; k > 0; --k) {
                const bool sw = lv[j][k] > lv[j][k-1];
                const float tv = sw ? lv[j][k-1] : lv[j][k];
                const int   ti = sw ? li[j][k-1] : li[j][k];
                lv[j][k-1] = sw ? lv[j][k] : lv[j][k-1];
                li[j][k-1] = sw ? li[j][k] : li[j][k-1];
                lv[j][k] = tv;  li[j][k] = ti;
            }
        }
    }

    // Merge with partner lane via u64 keys: (float_bits << 32) | (127 - idx).
    // value bits monotone (all >= 0); low bits larger for smaller idx -> desired order.
    unsigned long long mkey[4][K_];
    #pragma unroll
    for (int j = 0; j < 4; ++j) {
        unsigned long long a[K_], b[K_];
        #pragma unroll
        for (int k = 0; k < K_; ++k) {
            a[k] = ((unsigned long long)__float_as_uint(lv[j][k]) << 32)
                 | (unsigned int)(D_ - 1 - li[j][k]);
            const float pv = __shfl_xor(lv[j][k], 1);
            const int   pi = __shfl_xor(li[j][k], 1);
            b[k] = ((unsigned long long)__float_as_uint(pv) << 32)
                 | (unsigned int)(D_ - 1 - pi);
        }
        // bitonic: top-4 of (a desc ++ b asc), then sort the bitonic quad desc
        unsigned long long m0 = a[0] > b[3] ? a[0] : b[3];
        unsigned long long m1 = a[1] > b[2] ? a[1] : b[2];
        unsigned long long m2 = a[2] > b[1] ? a[2] : b[1];
        unsigned long long m3 = a[3] > b[0] ? a[3] : b[0];
        cswap_u64(m0, m2); cswap_u64(m1, m3);
        cswap_u64(m0, m1); cswap_u64(m2, m3);
        mkey[j][0] = m0; mkey[j][1] = m1; mkey[j][2] = m2; mkey[j][3] = m3;
    }

    // Write raw (unnormalized) top-4 values + depth channel. Even lane: pred, odd: dep.
    const int b_ = bc / C_, c_ = bc - b_ * C_;
    float4* predb = (float4*)out + (size_t)((b_*2*C_ + c_) * K_) * GPB + grp;
    float4* depb  = (float4*)out + (size_t)((b_*2*C_ + C_ + c_) * K_) * GPB + grp;
    if (half == 0) {
        #pragma unroll
        for (int k = 0; k < K_; ++k) {
            float4 pv;
            pv.x = __uint_as_float((unsigned int)(mkey[0][k] >> 32));
            pv.y = __uint_as_float((unsigned int)(mkey[1][k] >> 32));
            pv.z = __uint_as_float((unsigned int)(mkey[2][k] >> 32));
            pv.w = __uint_as_float((unsigned int)(mkey[3][k] >> 32));
            predb[(size_t)k * GPB] = pv;
        }
    } else {
        #pragma unroll
        for (int k = 0; k < K_; ++k) {
            float4 dv;
            dv.x = (float)(int)(mkey[0][k] & 0xFFu) / 127.0f;
            dv.y = (float)(int)(mkey[1][k] & 0xFFu) / 127.0f;
            dv.z = (float)(int)(mkey[2][k] & 0xFFu) / 127.0f;
            dv.w = (float)(int)(mkey[3][k] & 0xFFu) / 127.0f;
            depb[(size_t)k * GPB] = dv;
        }
    }

    // max of this thread's columns = top-1 of merged lists
    float mx = fmaxf(fmaxf(__uint_as_float((unsigned int)(mkey[0][0] >> 32)),
                           __uint_as_float((unsigned int)(mkey[1][0] >> 32))),
                     fmaxf(__uint_as_float((unsigned int)(mkey[2][0] >> 32)),
                           __uint_as_float((unsigned int)(mkey[3][0] >> 32))));

    // block reduce min/max -> one atomic pair per block (all threads in block share bc)
    #pragma unroll
    for (int off = 32; off > 0; off >>= 1) {
        mn = fminf(mn, __shfl_xor(mn, off));
        mx = fmaxf(mx, __shfl_xor(mx, off));
    }
    __shared__ float smn[4], smx[4];
    const int wave = threadIdx.x >> 6;
    if ((threadIdx.x & 63) == 0) { smn[wave] = mn; smx[wave] = mx; }
    __syncthreads();
    if (threadIdx.x == 0) {
        float bmn = fminf(fminf(smn[0], smn[1]), fminf(smn[2], smn[3]));
        float bmx = fmaxf(fmaxf(smx[0], smx[1]), fmaxf(smx[2], smx[3]));
        atomicMin(&mm[2*bc],   __float_as_uint(bmn));
        atomicMax(&mm[2*bc+1], __float_as_uint(bmx));
    }
}

// Normalize the pred channel in place: (v - mn) / ((mx - mn) + eps) * SCALE
__global__ __launch_bounds__(256) void norm_kernel(float* __restrict__ out,
                                                   const unsigned int* __restrict__ mm) {
    const int tid = blockIdx.x * 256 + threadIdx.x;   // float4 index over pred elements
    const int per_bc4 = K_ * HW_ / 4;                 // 65536
    const int bc = tid / per_bc4;
    if (bc >= NBC) return;
    const int b_ = bc / C_;
    const size_t n4 = (size_t)tid + (size_t)b_ * C_ * per_bc4;  // skip dep channels
    const float mnv = __uint_as_float(mm[2*bc]);
    const float mxv = __uint_as_float(mm[2*bc+1]);
    const float den = (mxv - mnv) + EPS_;
    float4 v = ((float4*)out)[n4];
    v.x = (v.x - mnv) / den * SCALE_;
    v.y = (v.y - mnv) / den * SCALE_;
    v.z = (v.z - mnv) / den * SCALE_;
    v.w = (v.w - mnv) / den * SCALE_;
    ((float4*)out)[n4] = v;
}

extern "C" void kernel_launch(void* const* d_in, const int* in_sizes, int n_in,
                              void* d_out, int out_size, void* d_ws, size_t ws_size,
                              hipStream_t stream) {
    const float* x = (const float*)d_in[0];
    float* out = (float*)d_out;
    unsigned int* mm = (unsigned int*)d_ws;

    hipLaunchKernelGGL(init_mm_kernel, dim3(1), dim3(64), 0, stream, mm);

    const int threads1 = NBC * GPB * 2;               // 131072
    hipLaunchKernelGGL(topk_kernel, dim3(threads1 / 256), dim3(256), 0, stream,
                       x, out, mm);

    const int threads2 = NBC * K_ * HW_ / 4;          // 262144
    hipLaunchKernelGGL(norm_kernel, dim3(threads2 / 256), dim3(256), 0, stream,
                       out, mm);
}